// Round 1
// baseline (1327.089 us; speedup 1.0000x reference)
//
#include <hip/hip_runtime.h>

#define TT 2048
#define FF 12
#define HH 96
#define CH 128
#define L2E 1.44269504088896340736f

__device__ __forceinline__ float fast_exp2(float x){ return __builtin_amdgcn_exp2f(x); }
__device__ __forceinline__ float fast_rcp(float x){ return __builtin_amdgcn_rcpf(x); }

// One block per batch element (256 blocks = 256 CUs), 512 threads = 8 waves.
// Wave w owns a 16-wide K-slice of the concatenated vector v = [h(96) | x(24pad) | pad]
// (waves 0..5: h, wave 6: x[0..16), wave 7: x[16..24)+zeros).
// Each thread holds W rows for 6 gates x 16 cols in registers (96 VGPRs).
__global__ __launch_bounds__(512, 2) void lstm_persist(
  const float* __restrict__ seq, const int* __restrict__ ev, const int* __restrict__ rsi,
  const int* __restrict__ len, const float* __restrict__ eemb, const float* __restrict__ remb,
  const float* __restrict__ W_ih, const float* __restrict__ W_hh,
  const float* __restrict__ b_ih, const float* __restrict__ b_hh,
  const float* __restrict__ W_mlp, const float* __restrict__ b_mlp,
  const float* __restrict__ W_fc, const float* __restrict__ b_fc,
  float* __restrict__ out)
{
  const int b   = blockIdx.x;
  const int tid = threadIdx.x;
  const int w   = tid >> 6;
  const int l   = tid & 63;

  __shared__ __align__(16) float vh[HH];          // h state (broadcast source)
  __shared__ __align__(16) float xch[CH][32];     // staged x chunk, rows padded to 32 floats
  __shared__ __align__(16) float part[6*8*64];    // [k][wave][lane] gate partials
  __shared__ __align__(16) float act[384];        // activated gates i,f,g,o
  __shared__ __align__(16) float lastk[3*HH];     // last-K h ring (zero-init)
  __shared__ __align__(16) float h2[2*HH];
  __shared__ __align__(16) float et[32*6];
  __shared__ __align__(16) float rt[8*3];
  __shared__ int evb[CH];
  __shared__ int rsb[CH];

  // ---- prologue: load per-thread weight slice into registers ----
  float wreg[96];
  if (w < 6) {
    #pragma unroll
    for (int k = 0; k < 6; ++k) {
      const int g = l + 64*k;
      const float* p = W_hh + g*96 + 16*w;
      #pragma unroll
      for (int i = 0; i < 16; ++i) wreg[k*16+i] = p[i];
    }
  } else if (w == 6) {
    #pragma unroll
    for (int k = 0; k < 6; ++k) {
      const int g = l + 64*k;
      const float* p = W_ih + g*21;           // cols 96..111 -> W_ih[0..16)
      #pragma unroll
      for (int i = 0; i < 16; ++i) wreg[k*16+i] = p[i];
    }
  } else {
    #pragma unroll
    for (int k = 0; k < 6; ++k) {
      const int g = l + 64*k;
      #pragma unroll
      for (int i = 0; i < 16; ++i) {          // cols 112..127 -> W_ih[16..21) then 0
        const int c = 16 + i;
        wreg[k*16+i] = (c < 21) ? W_ih[g*21 + c] : 0.f;
      }
    }
  }
  const float bg = (tid < 384) ? (b_ih[tid] + b_hh[tid]) : 0.f;

  for (int i = tid; i < HH;   i += 512) vh[i] = 0.f;
  for (int i = tid; i < 3*HH; i += 512) lastk[i] = 0.f;
  for (int i = tid; i < 192;  i += 512) et[i] = eemb[i];
  for (int i = tid; i < 24;   i += 512) rt[i] = remb[i];

  float c_state = 0.f;
  const int L = len[b];                        // state frozen past L; outputs past L unused

  for (int t0 = 0; t0 < L; t0 += CH) {
    // ---- stage 1: coalesced seq load + index load ----
    for (int q = tid; q < CH*FF; q += 512) {
      const int r = q / 12;
      const int c = q - r*12;
      xch[r][c] = seq[(size_t)b*(TT*FF) + (size_t)t0*FF + q];
    }
    if (tid < CH) {
      evb[tid] = ev [b*TT + t0 + tid];
      rsb[tid] = rsi[b*TT + t0 + tid];
    }
    __syncthreads();
    // ---- stage 2: embedding gather + zero pad (cols 12..31) ----
    for (int q = tid; q < CH*20; q += 512) {
      const int r  = q / 20;
      const int cc = q - r*20 + 12;
      float val;
      if (cc < 18)      val = et[evb[r]*6 + (cc-12)];
      else if (cc < 21) val = rt[rsb[r]*3 + (cc-18)];
      else              val = 0.f;
      xch[r][cc] = val;
    }
    __syncthreads();

    const int nr = min(CH, L - t0);
    for (int r = 0; r < nr; ++r) {
      // ---- phase A: gate partials (all 8 waves) ----
      const float* sp = (w < 6) ? (vh + 16*w) : (&xch[r][16*(w-6)]);
      const float4 q0 = ((const float4*)sp)[0];
      const float4 q1 = ((const float4*)sp)[1];
      const float4 q2 = ((const float4*)sp)[2];
      const float4 q3 = ((const float4*)sp)[3];
      const float xv[16] = {q0.x,q0.y,q0.z,q0.w, q1.x,q1.y,q1.z,q1.w,
                            q2.x,q2.y,q2.z,q2.w, q3.x,q3.y,q3.z,q3.w};
      #pragma unroll
      for (int k = 0; k < 6; ++k) {
        float a = 0.f;
        #pragma unroll
        for (int i = 0; i < 16; ++i) a = fmaf(wreg[k*16+i], xv[i], a);
        part[(k*8 + w)*64 + l] = a;            // conflict-free b32 write
      }
      __syncthreads();
      // ---- phase B: reduce 8 partials + activation (threads 0..383, gate=tid) ----
      if (tid < 384) {
        float s = bg;
        const int kk = tid >> 6;
        const int ll = tid & 63;
        #pragma unroll
        for (int ww = 0; ww < 8; ++ww) s += part[(kk*8 + ww)*64 + ll];
        const bool is_t = (tid >= 192) && (tid < 288);   // g-gate -> tanh, else sigmoid
        const float arg = is_t ? (-2.f*L2E)*fabsf(s) : (-L2E)*s;
        const float e  = fast_exp2(arg);
        const float r1 = fast_rcp(1.f + e);
        const float th = copysignf((1.f - e) * r1, s);
        act[tid] = is_t ? th : r1;
      }
      __syncthreads();
      // ---- phase C: c/h update (threads 0..95) ----
      if (tid < 96) {
        const float i_ = act[tid];
        const float f_ = act[96  + tid];
        const float g_ = act[192 + tid];
        const float o_ = act[288 + tid];
        c_state = fmaf(f_, c_state, i_*g_);
        const float e  = fast_exp2((-2.f*L2E)*fabsf(c_state));
        const float th = copysignf((1.f - e) * fast_rcp(1.f + e), c_state);
        const float hn = o_ * th;
        vh[tid] = hn;
        const int kk = (t0 + r) + 3 - L;       // last-K ring: t in [L-3, L)
        if (kk >= 0) lastk[kk*96 + tid] = hn;
      }
      __syncthreads();
    }
  }

  // ---- epilogue: h_fin = vh; h_lastk = relu(W_mlp @ lastk + b); out = W_fc @ [h_fin|h_lastk] + b ----
  if (tid < 192) {
    const int hh = tid / 96;
    const int m  = tid - hh*96;
    const float* wp = W_mlp + m*288 + hh*144;
    const float* xp = lastk + hh*144;
    float s = 0.f;
    #pragma unroll 8
    for (int i = 0; i < 144; ++i) s = fmaf(wp[i], xp[i], s);
    act[tid] = s;
  }
  __syncthreads();
  if (tid < 96) {
    const float hl = act[tid] + act[96+tid] + b_mlp[tid];
    h2[96 + tid] = fmaxf(hl, 0.f);
    h2[tid] = vh[tid];
  }
  __syncthreads();
  if (tid < 128) {
    const int o  = tid >> 6;
    const int ll = tid & 63;
    const float* wf = W_fc + o*192 + 3*ll;
    float s = fmaf(wf[0], h2[3*ll+0], fmaf(wf[1], h2[3*ll+1], wf[2]*h2[3*ll+2]));
    #pragma unroll
    for (int off = 32; off > 0; off >>= 1) s += __shfl_down(s, off);
    if (ll == 0) out[b*2 + o] = s + b_fc[o];
  }
}

extern "C" void kernel_launch(void* const* d_in, const int* in_sizes, int n_in,
                              void* d_out, int out_size, void* d_ws, size_t ws_size,
                              hipStream_t stream) {
  const float* seq   = (const float*)d_in[0];
  const int*   ev    = (const int*)  d_in[1];
  const int*   rsi   = (const int*)  d_in[2];
  const int*   len   = (const int*)  d_in[3];
  const float* eemb  = (const float*)d_in[4];
  const float* remb  = (const float*)d_in[5];
  const float* W_ih  = (const float*)d_in[6];
  const float* W_hh  = (const float*)d_in[7];
  const float* b_ih  = (const float*)d_in[8];
  const float* b_hh  = (const float*)d_in[9];
  const float* W_mlp = (const float*)d_in[10];
  const float* b_mlp = (const float*)d_in[11];
  const float* W_fc  = (const float*)d_in[12];
  const float* b_fc  = (const float*)d_in[13];

  hipLaunchKernelGGL(lstm_persist, dim3(256), dim3(512), 0, stream,
                     seq, ev, rsi, len, eemb, remb, W_ih, W_hh, b_ih, b_hh,
                     W_mlp, b_mlp, W_fc, b_fc, (float*)d_out);
}